// Round 6
// baseline (204.132 us; speedup 1.0000x reference)
//
#include <hip/hip_runtime.h>

// RGCN layer with skip on MI355X.
// out[n] = bias + skip_bias + x[n]@skipW^T + h[n]@rootW + sum_{e: dst=n} ew[e]*(h[src]@rel[etype])
//
// Round 5: CSR keyed by (dst*8 + type) -> accum has ONE float2 accumulator,
// 2 FMA/edge, direct segment flush to S (bf16). int2 edge payload.
// Fused bf16-MFMA GEMM  out = [S | h | x] @ [relF; rootW; skipW^T] + bb  unchanged.

constexpr int DIM  = 128;
constexpr int BM   = 64;
constexpr int KC   = 32;
constexpr int BPAD = 4;
constexpr int KTOT = 1280;        // 8*128 (S) + 128 (h) + 128 (x)
constexpr int SCAN_CHUNK = 2048;  // elements per scan block (256 thr x 8)

typedef __attribute__((ext_vector_type(8))) short     short8v;
typedef __attribute__((ext_vector_type(8))) unsigned short ushort8v;
typedef __attribute__((ext_vector_type(4))) float     float4v;

__device__ __forceinline__ unsigned short f2bf(float x) {
    union { float f; unsigned u; } c; c.f = x;
    unsigned u = c.u;
    u += 0x7fffu + ((u >> 16) & 1u);   // round-to-nearest-even
    return (unsigned short)(u >> 16);
}

// ---------------------------------------------------------------------------
// CSR build over M = N*8 segments, key = dst*8 + type
// ---------------------------------------------------------------------------
__global__ __launch_bounds__(256) void zero_i32_kernel(int* __restrict__ p, int n)
{
    int i = blockIdx.x * 256 + threadIdx.x;
    if (i < n) p[i] = 0;
}

__global__ __launch_bounds__(256) void hist_kernel(
    const int* __restrict__ ei, const int* __restrict__ et,
    int* __restrict__ counts, int E)
{
    int e = blockIdx.x * 256 + threadIdx.x;
    if (e < E) atomicAdd(&counts[ei[(long long)E + e] * 8 + (et[e] & 7)], 1);
}

// scan1: per-block local exclusive scan (2048 elems/block) + block totals
__global__ __launch_bounds__(256) void scan1_kernel(
    const int* __restrict__ counts, int* __restrict__ local,
    int* __restrict__ blockSums, int M)
{
    __shared__ int sh[256];
    const int b = blockIdx.x, t = threadIdx.x;
    const int base = b * SCAN_CHUNK + t * 8;

    int v[8];
    int s = 0;
    #pragma unroll
    for (int j = 0; j < 8; ++j) {
        int idx = base + j;
        v[j] = (idx < M) ? counts[idx] : 0;
        s += v[j];
    }
    sh[t] = s;
    __syncthreads();
    for (int off = 1; off < 256; off <<= 1) {
        int x = (t >= off) ? sh[t - off] : 0;
        __syncthreads();
        sh[t] += x;
        __syncthreads();
    }
    int ex = sh[t] - s;
    if (t == 255) blockSums[b] = sh[255];
    #pragma unroll
    for (int j = 0; j < 8; ++j) {
        int idx = base + j;
        if (idx < M) { local[idx] = ex; ex += v[j]; }
    }
}

// scan2: single small block scans the block totals (nb <= 1024), exclusive in place
__global__ __launch_bounds__(1024) void scan2_kernel(int* __restrict__ bs, int nb)
{
    __shared__ int sh[1024];
    const int t = threadIdx.x;
    int v = (t < nb) ? bs[t] : 0;
    sh[t] = v;
    __syncthreads();
    for (int off = 1; off < 1024; off <<= 1) {
        int x = (t >= off) ? sh[t - off] : 0;
        __syncthreads();
        sh[t] += x;
        __syncthreads();
    }
    if (t < nb) bs[t] = sh[t] - v;
}

// scan3: add block offset; emit offsets and cursor; offsets[M] = E
__global__ __launch_bounds__(256) void scan3_kernel(
    int* __restrict__ offsets, const int* __restrict__ blockSums,
    int* __restrict__ cursor, int M, int E)
{
    const int b = blockIdx.x, t = threadIdx.x;
    const int add = blockSums[b];
    #pragma unroll
    for (int j = 0; j < 8; ++j) {
        int idx = b * SCAN_CHUNK + j * 256 + t;
        if (idx < M) {
            int v = offsets[idx] + add;
            offsets[idx] = v;
            cursor[idx]  = v;
        }
    }
    if (b == 0 && t == 0) offsets[M] = E;
}

// sort edge payloads by (dst,type): payload[pos] = (src, bits(weight))
__global__ __launch_bounds__(256) void scatter_kernel(
    const int* __restrict__ ei, const int* __restrict__ et,
    const float* __restrict__ ew, int* __restrict__ cursor,
    int2* __restrict__ payload, int E)
{
    int e = blockIdx.x * 256 + threadIdx.x;
    if (e < E) {
        int key = ei[(long long)E + e] * 8 + (et[e] & 7);
        int pos = atomicAdd(&cursor[key], 1);
        payload[pos] = make_int2(ei[e], __float_as_int(ew[e]));
    }
}

// ---------------------------------------------------------------------------
// one wave per dst node; per type-segment a single float2 acc (2 FMA/edge),
// flushed straight to S[n, r*128 + :] as bf16. Empty segments write zeros.
// ---------------------------------------------------------------------------
__global__ __launch_bounds__(256) void accum_kernel(
    const int2* __restrict__ payload, const float* __restrict__ h,
    const int* __restrict__ offsets, unsigned short* __restrict__ S, int N)
{
    const int n    = blockIdx.x * 4 + (threadIdx.x >> 6);
    const int lane = threadIdx.x & 63;
    if (n >= N) return;

    const int segBase = n * 8;
    int s1 = offsets[segBase];

    for (int r = 0; r < 8; ++r) {
        const int s0 = s1;
        s1 = offsets[segBase + r + 1];

        float accx = 0.f, accy = 0.f;
        int o = s0;
        for (; o + 2 <= s1; o += 2) {
            const int2 p0 = payload[o];
            const int2 p1 = payload[o + 1];
            const float2 h0 = *reinterpret_cast<const float2*>(
                h + (size_t)p0.x * DIM + lane * 2);
            const float2 h1 = *reinterpret_cast<const float2*>(
                h + (size_t)p1.x * DIM + lane * 2);
            const float w0 = __int_as_float(p0.y);
            const float w1 = __int_as_float(p1.y);
            accx += w0 * h0.x + w1 * h1.x;
            accy += w0 * h0.y + w1 * h1.y;
        }
        if (o < s1) {
            const int2 p0 = payload[o];
            const float2 h0 = *reinterpret_cast<const float2*>(
                h + (size_t)p0.x * DIM + lane * 2);
            const float w0 = __int_as_float(p0.y);
            accx += w0 * h0.x;
            accy += w0 * h0.y;
        }

        unsigned pk = (unsigned)f2bf(accx) | ((unsigned)f2bf(accy) << 16);
        *reinterpret_cast<unsigned*>(
            &S[(size_t)n * 1024 + r * DIM + lane * 2]) = pk;
    }
}

// ---------------------------------------------------------------------------
// Bt[f][k] (bf16, k-major per output col): k<1024 -> relF[k][f];
// 1024..1151 -> rootW[k-1024][f]; 1152..1279 -> skipW[f][k-1152]
// ---------------------------------------------------------------------------
__global__ __launch_bounds__(256) void repack_B_kernel(
    const float* __restrict__ relF, const float* __restrict__ rootW,
    const float* __restrict__ skipW, unsigned short* __restrict__ Bt)
{
    int idx = blockIdx.x * 256 + threadIdx.x;
    if (idx >= DIM * KTOT) return;
    int f = idx / KTOT, k = idx % KTOT;
    float v;
    if (k < 1024)       v = relF[(size_t)k * DIM + f];
    else if (k < 1152)  v = rootW[(k - 1024) * DIM + f];
    else                v = skipW[f * DIM + (k - 1152)];
    Bt[(size_t)f * KTOT + k] = f2bf(v);
}

// ---------------------------------------------------------------------------
// out[n0+i][j] = sum_k A[i][k]*B[k][j] + bias[j] + skipB[j]
// A = [S(bf16) | h(f32->bf16) | x(f32->bf16)], B from Bt.
// 256 thr = 4 waves 2x2, 64x64 out each; BM=BN=128, BK=64; XOR-swizzled LDS.
// ---------------------------------------------------------------------------
__global__ __launch_bounds__(256) void mfma_gemm_kernel(
    const unsigned short* __restrict__ S, const float* __restrict__ h,
    const float* __restrict__ x, const unsigned short* __restrict__ Bt,
    const float* __restrict__ bias, const float* __restrict__ skipB,
    float* __restrict__ out, int N)
{
    __shared__ unsigned short As[128 * 64];   // [row][k] swizzled, 16 KiB
    __shared__ unsigned short Bs[128 * 64];   // [col][k] swizzled, 16 KiB

    const int tid  = threadIdx.x;
    const int lane = tid & 63;
    const int wid  = tid >> 6;
    const int wr   = wid >> 1, wc = wid & 1;
    const int l15  = lane & 15, l4 = lane >> 4;
    const int n0   = blockIdx.x * 128;

    float4v acc[4][4];
    #pragma unroll
    for (int m = 0; m < 4; ++m)
        #pragma unroll
        for (int nn = 0; nn < 4; ++nn)
            acc[m][nn] = (float4v)0.f;

    for (int k0 = 0; k0 < KTOT; k0 += 64) {
        __syncthreads();
        // ---- stage A tile [128 rows][64 k] ----
        if (k0 < 1024) {
            #pragma unroll
            for (int i = 0; i < 4; ++i) {
                int idx = tid + i * 256;          // 0..1023
                int row = idx >> 3, c8 = idx & 7;
                int n = n0 + row;
                ushort8v v = (ushort8v)0;
                if (n < N)
                    v = *reinterpret_cast<const ushort8v*>(
                        &S[(size_t)n * 1024 + k0 + c8 * 8]);
                int bo = row * 128 + ((c8 * 16) ^ ((row & 7) << 4));
                *reinterpret_cast<ushort8v*>((char*)As + bo) = v;
            }
        } else {
            const float* __restrict__ A = (k0 < 1152) ? h : x;
            const int kb = (k0 < 1152) ? (k0 - 1024) : (k0 - 1152);
            #pragma unroll
            for (int i = 0; i < 8; ++i) {
                int idx = tid + i * 256;          // 0..2047
                int row = idx >> 4, c4 = idx & 15;
                int n = n0 + row;
                float4 v = make_float4(0.f, 0.f, 0.f, 0.f);
                if (n < N)
                    v = *reinterpret_cast<const float4*>(
                        &A[(size_t)n * DIM + kb + c4 * 4]);
                unsigned short b4[4] = { f2bf(v.x), f2bf(v.y), f2bf(v.z), f2bf(v.w) };
                int bo = row * 128 + ((c4 * 8) ^ ((row & 7) << 4));
                *reinterpret_cast<ulonglong1*>((char*)As + bo) =
                    *reinterpret_cast<const ulonglong1*>(b4);
            }
        }
        // ---- stage B tile [128 cols][64 k] from Bt[f][KTOT] ----
        #pragma unroll
        for (int i = 0; i < 4; ++i) {
            int idx = tid + i * 256;              // 0..1023
            int col = idx >> 3, c8 = idx & 7;
            ushort8v v = *reinterpret_cast<const ushort8v*>(
                &Bt[(size_t)col * KTOT + k0 + c8 * 8]);
            int bo = col * 128 + ((c8 * 16) ^ ((col & 7) << 4));
            *reinterpret_cast<ushort8v*>((char*)Bs + bo) = v;
        }
        __syncthreads();

        // ---- MFMA: 2 sub-steps of K=32 ----
        #pragma unroll
        for (int s = 0; s < 2; ++s) {
            const int kk = s * 32 + l4 * 8;       // this lane's k start
            short8v a[4], b[4];
            #pragma unroll
            for (int m = 0; m < 4; ++m) {
                int row = wr * 64 + m * 16 + l15;
                int bo = row * 128 + ((kk * 2) ^ ((row & 7) << 4));
                a[m] = *reinterpret_cast<const short8v*>((const char*)As + bo);
            }
            #pragma unroll
            for (int nn = 0; nn < 4; ++nn) {
                int col = wc * 64 + nn * 16 + l15;
                int bo = col * 128 + ((kk * 2) ^ ((col & 7) << 4));
                b[nn] = *reinterpret_cast<const short8v*>((const char*)Bs + bo);
            }
            #pragma unroll
            for (int m = 0; m < 4; ++m)
                #pragma unroll
                for (int nn = 0; nn < 4; ++nn)
                    acc[m][nn] = __builtin_amdgcn_mfma_f32_16x16x32_bf16(
                        a[m], b[nn], acc[m][nn], 0, 0, 0);
        }
    }

    // ---- epilogue: out = acc + bias + skipB ----
    #pragma unroll
    for (int nn = 0; nn < 4; ++nn) {
        const int col = wc * 64 + nn * 16 + l15;
        const float bb = bias[col] + skipB[col];
        #pragma unroll
        for (int m = 0; m < 4; ++m) {
            #pragma unroll
            for (int j = 0; j < 4; ++j) {
                int row = wr * 64 + m * 16 + l4 * 4 + j;
                int n = n0 + row;
                if (n < N)
                    out[(size_t)n * DIM + col] = acc[m][nn][j] + bb;
            }
        }
    }
}

// ---------------------------------------------------------------------------
// fallback kernels (round 0/1) in case ws is too small or R != 8
// ---------------------------------------------------------------------------
__global__ __launch_bounds__(256) void base_kernel(
    const float* __restrict__ x, const float* __restrict__ h,
    const float* __restrict__ skipW, const float* __restrict__ rootW,
    const float* __restrict__ bias, const float* __restrict__ skipB,
    float* __restrict__ out, int N)
{
    __shared__ float As2[BM][KC];
    __shared__ float Bs2[KC][DIM + BPAD];

    const int tid = threadIdx.x;
    const int n0  = blockIdx.x * BM;
    const int f0  = (tid & 31) * 4;
    const int r0  = (tid >> 5) * 8;

    float acc[8][4] = {};

    for (int phase = 0; phase < 2; ++phase) {
        const float* __restrict__ A = phase ? h : x;
        for (int d0 = 0; d0 < DIM; d0 += KC) {
            __syncthreads();
            for (int idx = tid; idx < BM * KC; idx += 256) {
                int r = idx / KC, dd = idx % KC;
                int n = n0 + r;
                As2[r][dd] = (n < N) ? A[(long long)n * DIM + d0 + dd] : 0.f;
            }
            if (phase == 0) {
                for (int idx = tid; idx < DIM * KC; idx += 256) {
                    int f = idx / KC, dd = idx % KC;
                    Bs2[dd][f] = skipW[f * DIM + d0 + dd];
                }
            } else {
                for (int idx = tid; idx < KC * DIM; idx += 256) {
                    int dd = idx / DIM, f = idx % DIM;
                    Bs2[dd][f] = rootW[(d0 + dd) * DIM + f];
                }
            }
            __syncthreads();
            #pragma unroll
            for (int dd = 0; dd < KC; ++dd) {
                float a[8];
                #pragma unroll
                for (int i = 0; i < 8; ++i) a[i] = As2[r0 + i][dd];
                const float4 b = *reinterpret_cast<const float4*>(&Bs2[dd][f0]);
                #pragma unroll
                for (int i = 0; i < 8; ++i) {
                    acc[i][0] += a[i] * b.x; acc[i][1] += a[i] * b.y;
                    acc[i][2] += a[i] * b.z; acc[i][3] += a[i] * b.w;
                }
            }
        }
    }

    float bb[4];
    #pragma unroll
    for (int j = 0; j < 4; ++j) bb[j] = bias[f0 + j] + skipB[f0 + j];
    #pragma unroll
    for (int i = 0; i < 8; ++i) {
        int n = n0 + r0 + i;
        if (n < N) {
            float4 v = make_float4(acc[i][0] + bb[0], acc[i][1] + bb[1],
                                   acc[i][2] + bb[2], acc[i][3] + bb[3]);
            *reinterpret_cast<float4*>(&out[(long long)n * DIM + f0]) = v;
        }
    }
}

__global__ __launch_bounds__(256) void hrel_kernel(
    const float* __restrict__ h, const float* __restrict__ rel,
    float* __restrict__ hrel, int N, int R)
{
    __shared__ float As2[BM][KC];
    __shared__ float Bs2[KC][DIM + BPAD];

    const int tid = threadIdx.x;
    const int n0  = blockIdx.x * BM;
    const int rr  = blockIdx.y;
    const float* __restrict__ B = rel + (size_t)rr * DIM * DIM;
    const int f0  = (tid & 31) * 4;
    const int r0  = (tid >> 5) * 8;

    float acc[8][4] = {};

    for (int d0 = 0; d0 < DIM; d0 += KC) {
        __syncthreads();
        for (int idx = tid; idx < BM * KC; idx += 256) {
            int r = idx / KC, dd = idx % KC;
            int n = n0 + r;
            As2[r][dd] = (n < N) ? h[(long long)n * DIM + d0 + dd] : 0.f;
        }
        for (int idx = tid; idx < KC * DIM; idx += 256) {
            int dd = idx / DIM, f = idx % DIM;
            Bs2[dd][f] = B[(d0 + dd) * DIM + f];
        }
        __syncthreads();
        #pragma unroll
        for (int dd = 0; dd < KC; ++dd) {
            float a[8];
            #pragma unroll
            for (int i = 0; i < 8; ++i) a[i] = As2[r0 + i][dd];
            const float4 b = *reinterpret_cast<const float4*>(&Bs2[dd][f0]);
            #pragma unroll
            for (int i = 0; i < 8; ++i) {
                acc[i][0] += a[i] * b.x; acc[i][1] += a[i] * b.y;
                acc[i][2] += a[i] * b.z; acc[i][3] += a[i] * b.w;
            }
        }
    }

    #pragma unroll
    for (int i = 0; i < 8; ++i) {
        int n = n0 + r0 + i;
        if (n < N) {
            float4 v = make_float4(acc[i][0], acc[i][1], acc[i][2], acc[i][3]);
            *reinterpret_cast<float4*>(&hrel[((long long)n * R + rr) * DIM + f0]) = v;
        }
    }
}

__global__ __launch_bounds__(256) void edge_kernel(
    const int* __restrict__ ei, const int* __restrict__ et,
    const float* __restrict__ ew, const float* __restrict__ hrel,
    float* __restrict__ out, int E, int R)
{
    const int tid  = threadIdx.x;
    const int lane = tid & 31;
    const long long e = (long long)blockIdx.x * 8 + (tid >> 5);
    if (e >= E) return;

    const int   src = ei[e];
    const int   dst = ei[(long long)E + e];
    const int   r   = et[e];
    const float w   = ew[e];

    const float4 v = reinterpret_cast<const float4*>(
        hrel + ((long long)src * R + r) * DIM)[lane];

    float* o = out + (long long)dst * DIM + lane * 4;
    atomicAdd(o + 0, v.x * w);
    atomicAdd(o + 1, v.y * w);
    atomicAdd(o + 2, v.z * w);
    atomicAdd(o + 3, v.w * w);
}

__global__ __launch_bounds__(256) void edge_direct_kernel(
    const int* __restrict__ ei, const int* __restrict__ et,
    const float* __restrict__ ew, const float* __restrict__ h,
    const float* __restrict__ rel, float* __restrict__ out, int E)
{
    const int wid  = threadIdx.x >> 6;
    const int lane = threadIdx.x & 63;
    const long long e = (long long)blockIdx.x * 4 + wid;
    if (e >= E) return;

    const int   src = ei[e];
    const int   dst = ei[(long long)E + e];
    const int   r   = et[e];
    const float w   = ew[e];

    const float* __restrict__ hrow = h + (long long)src * DIM;
    const float* __restrict__ W    = rel + (size_t)r * DIM * DIM;

    float acc0 = 0.f, acc1 = 0.f;
    #pragma unroll 8
    for (int d = 0; d < DIM; ++d) {
        float hv = hrow[d];
        acc0 += hv * W[d * DIM + lane];
        acc1 += hv * W[d * DIM + lane + 64];
    }
    atomicAdd(&out[(long long)dst * DIM + lane],      acc0 * w);
    atomicAdd(&out[(long long)dst * DIM + lane + 64], acc1 * w);
}

// ---------------------------------------------------------------------------
extern "C" void kernel_launch(void* const* d_in, const int* in_sizes, int n_in,
                              void* d_out, int out_size, void* d_ws, size_t ws_size,
                              hipStream_t stream)
{
    const float* x     = (const float*)d_in[0];
    const float* h     = (const float*)d_in[1];
    const int*   ei    = (const int*)  d_in[2];
    const int*   et    = (const int*)  d_in[3];
    const float* ew    = (const float*)d_in[4];
    const float* rel   = (const float*)d_in[5];
    const float* rootW = (const float*)d_in[6];
    const float* bias  = (const float*)d_in[7];
    const float* skipW = (const float*)d_in[8];
    const float* skipB = (const float*)d_in[9];
    float* out = (float*)d_out;

    const int N = in_sizes[0] / DIM;           // 50000
    const int E = in_sizes[3];                 // 600000
    const int R = in_sizes[5] / (DIM * DIM);   // 8

    const int M = N * 8;                       // CSR segments = (node, type)
    const int nbScan = (M + SCAN_CHUNK - 1) / SCAN_CHUNK;

    // workspace layout
    const size_t S_elems  = (size_t)N * 1024;          // bf16
    const size_t Bt_elems = (size_t)DIM * KTOT;        // bf16
    const size_t need_new = S_elems * 2 + Bt_elems * 2
                          + ((size_t)(M + 1) + M + 1024) * sizeof(int)
                          + (size_t)E * sizeof(int2);

    if (R == 8 && nbScan <= 1024 && ws_size >= need_new) {
        unsigned short* S  = (unsigned short*)d_ws;
        unsigned short* Bt = S + S_elems;
        int*   offsets   = (int*)(Bt + Bt_elems);      // M+1
        int*   cursor    = offsets + (M + 1);          // M (counts, then cursor)
        int*   blockSums = cursor + M;                 // 1024
        int2*  payload   = (int2*)(blockSums + 1024);  // E

        zero_i32_kernel<<<dim3((M + 255) / 256), 256, 0, stream>>>(cursor, M);
        hist_kernel<<<dim3((E + 255) / 256), 256, 0, stream>>>(ei, et, cursor, E);
        scan1_kernel<<<dim3(nbScan), 256, 0, stream>>>(cursor, offsets, blockSums, M);
        scan2_kernel<<<dim3(1), 1024, 0, stream>>>(blockSums, nbScan);
        scan3_kernel<<<dim3(nbScan), 256, 0, stream>>>(offsets, blockSums, cursor, M, E);
        scatter_kernel<<<dim3((E + 255) / 256), 256, 0, stream>>>(
            ei, et, ew, cursor, payload, E);
        repack_B_kernel<<<dim3((DIM * KTOT + 255) / 256), 256, 0, stream>>>(
            rel, rootW, skipW, Bt);
        accum_kernel<<<dim3((N + 3) / 4), 256, 0, stream>>>(
            payload, h, offsets, S, N);
        mfma_gemm_kernel<<<dim3((N + 127) / 128), 256, 0, stream>>>(
            S, h, x, Bt, bias, skipB, out, N);
    } else {
        base_kernel<<<dim3((N + BM - 1) / BM), 256, 0, stream>>>(
            x, h, skipW, rootW, bias, skipB, out, N);
        if (ws_size >= (size_t)N * R * DIM * sizeof(float)) {
            float* hrel = (float*)d_ws;
            hrel_kernel<<<dim3((N + BM - 1) / BM, R), 256, 0, stream>>>(h, rel, hrel, N, R);
            edge_kernel<<<dim3((E + 7) / 8), 256, 0, stream>>>(ei, et, ew, hrel, out, E, R);
        } else {
            edge_direct_kernel<<<dim3((E + 3) / 4), 256, 0, stream>>>(ei, et, ew, h, rel, out, E);
        }
    }
}